// Round 1
// 70.853 us; speedup vs baseline: 1.0208x; 1.0208x over previous
//
#include <hip/hip_runtime.h>
#include <math.h>

// Problem constants (hardcoded in reference)
#define V 2048
#define DF 128
#define NK 73            // 1 + J + J^2 branch outputs
#define CH 8             // W-rows per block in the fused kernel
#define G1 (V / CH)      // 256 blocks -> 1 block/CU, 8 waves/CU
#define OUT_N (NK * DF)  // 9344
#define A_F 0.34657359027997264f   // A = R*ln(2)/(J-R+1) = ln2/2
#define TWO_PI_F 6.283185307179586f

// Fused scattering: Lmat = diag(deg)*dhalf^2 is exactly diagonal, so every
// filter matrix is diag(h_j(deg[v])) and the only cross-v coupling is the
// final mean. One kernel does: rowsum(W) -> filter responses -> all-73-branch
// accumulation, reading W once (16.8 MB) and f once (1 MB).
//
// Block = 512 threads = 8 waves, owns rows v0..v0+7.
//  Phase 1: thread t reads float4 #t of each row (1 KB/wave-instr, coalesced),
//           butterfly within wave, 8x8 wave partials through LDS.
//  Phase 2: 64 threads compute the 8x8 filter matrix wmat[row][j]
//           (wmat[r][0] = scaling) with EXACTLY the reference math.
//  Phase 3: 4 replicas (wave pairs) split the 73 branches: rep0 k0..18,
//           rep1 k19..36, rep2 k37..54, rep3 k55..72. acc[19] in registers,
//           fully static indexing (specialized per rep -> no scratch).
//           f loads are hoisted to the top so HBM latency hides under W reads.
// Partials: partial[b][k*128+d], 256 x 37 KB = 9.6 MB, coalesced stores.
__global__ __launch_bounds__(512) void k_fused(const float* __restrict__ W,
                                               const float* __restrict__ f,
                                               float* __restrict__ partial) {
    const int b = blockIdx.x;
    const int t = threadIdx.x;
    const int wave = t >> 6, lane = t & 63;
    const int v0 = b * CH;
    const int d = t & 127;

    __shared__ float wps[8][CH];                 // per-wave rowsum partials
    __shared__ __align__(16) float wmat[CH][8];  // [row][filter], [r][0]=scaling

    // Hoist f loads (independent of phase 1; latency hides under W reads).
    float fvv[CH];
    #pragma unroll
    for (int r = 0; r < CH; ++r)
        fvv[r] = f[(v0 + r) * DF + d];

    // ---- Phase 1: rowsums of the block's 8 W-rows ----
    float p[CH];
    #pragma unroll
    for (int r = 0; r < CH; ++r) {
        float4 x = ((const float4*)(W + (size_t)(v0 + r) * V))[t];
        p[r] = (x.x + x.y) + (x.z + x.w);
    }
    #pragma unroll
    for (int off = 32; off > 0; off >>= 1) {
        #pragma unroll
        for (int r = 0; r < CH; ++r) p[r] += __shfl_xor(p[r], off, 64);
    }
    if (lane == 0) {
        #pragma unroll
        for (int r = 0; r < CH; ++r) wps[wave][r] = p[r];
    }
    __syncthreads();

    // ---- Phase 2: filter responses (reference math, uniform branches) ----
    if (t < 64) {
        const int r = t >> 3, jj = t & 7;   // jj>=1 -> wavelet j=jj+1
        if (jj > 0) {
            float deg = 0.0f;
            #pragma unroll
            for (int wv = 0; wv < 8; ++wv) deg += wps[wv][r];
            float e = fabsf(deg / fmaxf(1.0f, deg));
            float x = logf(e);
            float tt = x - A_F * (float)jj * (1.0f / 3.0f);   // R = 3
            float val = 0.0f;
            if (tt > -A_F && tt <= 0.0f)
                val = 0.5f + 0.5f * cosf(TWO_PI_F * (tt / A_F + 0.5f));
            wmat[r][jj] = val;
        }
    }
    __syncthreads();
    if (t < CH) {
        float sumsq = 0.0f;
        #pragma unroll
        for (int jj = 1; jj < 8; ++jj) sumsq += wmat[t][jj] * wmat[t][jj];
        // (R/2)(d0^2+d1^2) + (R/2)d0^2 - sum wav^2 = 1.125 - sumsq
        wmat[t][0] = sqrtf(fmaxf(1.125f - sumsq, 0.0f));
    }
    __syncthreads();

    // ---- Phase 3: branch accumulation, 73 branches split over 4 replicas ----
    const int rep = t >> 7;   // uniform per wave pair -> no divergence
    float acc[19];
    #pragma unroll
    for (int i = 0; i < 19; ++i) acc[i] = 0.0f;

    #pragma unroll
    for (int r = 0; r < CH; ++r) {
        const float fv = fvv[r];
        const float af = fabsf(fv);
        const float4 wa = *(const float4*)&wmat[r][0];   // broadcast LDS reads
        const float4 wb = *(const float4*)&wmat[r][4];
        const float w0 = wa.x, w1 = wa.y, w2 = wa.z, w3 = wa.w;
        const float w4 = wb.x, w5 = wb.y, w6 = wb.z, w7 = wb.w;
        if (rep == 0) {
            // k=0 (raw mean), k=1..8 (layer 1), k=9..16 (u=0), k=17..18 (u=1,j=0..1)
            acc[0] += fv;
            acc[1] += w0 * af; acc[2] += w1 * af; acc[3] += w2 * af; acc[4] += w3 * af;
            acc[5] += w4 * af; acc[6] += w5 * af; acc[7] += w6 * af; acc[8] += w7 * af;
            const float c0 = w0 * af;
            acc[9]  += c0 * w0; acc[10] += c0 * w1; acc[11] += c0 * w2; acc[12] += c0 * w3;
            acc[13] += c0 * w4; acc[14] += c0 * w5; acc[15] += c0 * w6; acc[16] += c0 * w7;
            const float c1 = w1 * af;
            acc[17] += c1 * w0; acc[18] += c1 * w1;
        } else if (rep == 1) {
            // k=19..24 (u=1,j=2..7), k=25..32 (u=2), k=33..36 (u=3,j=0..3)
            const float c1 = w1 * af;
            acc[0] += c1 * w2; acc[1] += c1 * w3; acc[2] += c1 * w4;
            acc[3] += c1 * w5; acc[4] += c1 * w6; acc[5] += c1 * w7;
            const float c2 = w2 * af;
            acc[6]  += c2 * w0; acc[7]  += c2 * w1; acc[8]  += c2 * w2; acc[9]  += c2 * w3;
            acc[10] += c2 * w4; acc[11] += c2 * w5; acc[12] += c2 * w6; acc[13] += c2 * w7;
            const float c3 = w3 * af;
            acc[14] += c3 * w0; acc[15] += c3 * w1; acc[16] += c3 * w2; acc[17] += c3 * w3;
        } else if (rep == 2) {
            // k=37..40 (u=3,j=4..7), k=41..48 (u=4), k=49..54 (u=5,j=0..5)
            const float c3 = w3 * af;
            acc[0] += c3 * w4; acc[1] += c3 * w5; acc[2] += c3 * w6; acc[3] += c3 * w7;
            const float c4 = w4 * af;
            acc[4]  += c4 * w0; acc[5]  += c4 * w1; acc[6]  += c4 * w2; acc[7]  += c4 * w3;
            acc[8]  += c4 * w4; acc[9]  += c4 * w5; acc[10] += c4 * w6; acc[11] += c4 * w7;
            const float c5 = w5 * af;
            acc[12] += c5 * w0; acc[13] += c5 * w1; acc[14] += c5 * w2;
            acc[15] += c5 * w3; acc[16] += c5 * w4; acc[17] += c5 * w5;
        } else {
            // k=55..56 (u=5,j=6..7), k=57..64 (u=6), k=65..72 (u=7)
            const float c5 = w5 * af;
            acc[0] += c5 * w6; acc[1] += c5 * w7;
            const float c6 = w6 * af;
            acc[2] += c6 * w0; acc[3] += c6 * w1; acc[4] += c6 * w2; acc[5] += c6 * w3;
            acc[6] += c6 * w4; acc[7] += c6 * w5; acc[8] += c6 * w6; acc[9] += c6 * w7;
            const float c7 = w7 * af;
            acc[10] += c7 * w0; acc[11] += c7 * w1; acc[12] += c7 * w2; acc[13] += c7 * w3;
            acc[14] += c7 * w4; acc[15] += c7 * w5; acc[16] += c7 * w6; acc[17] += c7 * w7;
        }
    }

    const int kbase = (rep == 0) ? 0 : 1 + rep * 18;   // 0,19,37,55
    const int nacc  = (rep == 0) ? 19 : 18;
    float* pb = partial + (size_t)b * OUT_N + d;
    #pragma unroll
    for (int i = 0; i < 19; ++i)
        if (i < nacc) pb[(kbase + i) * DF] = acc[i];   // 256 B/wave-instr, coalesced
}

// Reduce the 256 block partials (9.6 MB, L3-resident), apply 1/V.
// Block = 256 threads handles 32 output elements: thread (o=t&31, g=t>>5)
// sums the contiguous b-range [g*32, g*32+32) (keeps b-order sequential),
// then an LDS tree combines the 8 groups in ascending order.
__global__ __launch_bounds__(256) void k_out(const float* __restrict__ partial,
                                             float* __restrict__ out) {
    const int t = threadIdx.x;
    const int o = t & 31, g = t >> 5;
    const int i0 = blockIdx.x * 32;
    float s = 0.0f;
    #pragma unroll
    for (int kk = 0; kk < 32; ++kk)
        s += partial[(size_t)(g * 32 + kk) * OUT_N + i0 + o];
    __shared__ float red[8][32];
    red[g][o] = s;
    __syncthreads();
    if (t < 32) {
        float tot = 0.0f;
        #pragma unroll
        for (int gg = 0; gg < 8; ++gg) tot += red[gg][t];
        out[i0 + t] = tot * (1.0f / (float)V);
    }
}

extern "C" void kernel_launch(void* const* d_in, const int* in_sizes, int n_in,
                              void* d_out, int out_size, void* d_ws, size_t ws_size,
                              hipStream_t stream) {
    const float* W = (const float*)d_in[0];   // fp32 [V,V]
    const float* f = (const float*)d_in[1];   // fp32 [V,DF]
    float* out = (float*)d_out;               // fp32 [NK*DF]

    float* partial = (float*)d_ws;            // G1 * OUT_N floats = 9.57 MB

    k_fused<<<G1, 512, 0, stream>>>(W, f, partial);
    k_out<<<OUT_N / 32, 256, 0, stream>>>(partial, out);
}